// Round 6
// baseline (225.009 us; speedup 1.0000x reference)
//
#include <hip/hip_runtime.h>
#include <math.h>

#define N_NODES 100000
#define D_INPUT 128
#define FDIM 128
#define A_HEADS 8
#define B_SEGS 512
#define D_OUTPUT 64
#define H_DIM 2304

typedef __attribute__((ext_vector_type(8))) __bf16 bf16x8;
typedef __attribute__((ext_vector_type(4))) float f32x4;

static __device__ inline unsigned short f2bfu(float f) {
    unsigned u = __builtin_bit_cast(unsigned, f);
    u += 0x7fffu + ((u >> 16) & 1u);
    return (unsigned short)(u >> 16);
}
static __device__ inline unsigned packbf(float a, float b) {
    return (unsigned)f2bfu(a) | ((unsigned)f2bfu(b) << 16);
}
static __device__ inline float bfl(unsigned u) {
    unsigned x = u << 16; return __builtin_bit_cast(float, x);
}
static __device__ inline float bfh(unsigned u) {
    unsigned x = u & 0xffff0000u; return __builtin_bit_cast(float, x);
}
static __device__ inline bf16x8 pack8(float4 a, float4 b) {
    union { unsigned u[4]; bf16x8 v; } r;
    r.u[0] = packbf(a.x, a.y); r.u[1] = packbf(a.z, a.w);
    r.u[2] = packbf(b.x, b.y); r.u[3] = packbf(b.z, b.w);
    return r.v;
}

// ---------------- segment boundaries (batch is sorted) ----------------
__global__ void seg_bounds_kernel(const int* __restrict__ batch, int n,
                                  int* __restrict__ seg_start) {
    int b = threadIdx.x;
    if (b > B_SEGS) return;
    int lo = 0, hi = n;
    while (lo < hi) {
        int mid = (lo + hi) >> 1;
        if (batch[mid] < b) lo = mid + 1; else hi = mid;
    }
    seg_start[b] = lo;
}

// ------- one-time weight conversion fp32 -> bf16 (packed u32), global -------
// Wb [128][64]u32, Wa [16][64]u32 (rows 8..15 zero), Wo [64][128]u32 (K 0..255),
// Wagg [64][1024]u32 (W_out cols 256..2303)
__global__ __launch_bounds__(256) void wconv_kernel(
        const float* __restrict__ W_in, const float* __restrict__ W_a,
        const float* __restrict__ W_out, unsigned* __restrict__ Wb,
        unsigned* __restrict__ Wa, unsigned* __restrict__ Wo,
        unsigned* __restrict__ Wagg) {
    int i = blockIdx.x * 256 + threadIdx.x;
    if (i < 8192) {
        float2 v = *(const float2*)(W_in + (size_t)i * 2);
        Wb[i] = packbf(v.x, v.y);
    } else if (i < 9216) {
        int j = i - 8192;
        if (j < 512) {
            float2 v = *(const float2*)(W_a + (size_t)j * 2);
            Wa[j] = packbf(v.x, v.y);
        } else Wa[j] = 0u;
    } else if (i < 17408) {
        int j = i - 9216;
        int row = j >> 7, cu = j & 127;
        float2 v = *(const float2*)(W_out + (size_t)row * H_DIM + cu * 2);
        Wo[j] = packbf(v.x, v.y);
    } else if (i < 82944) {
        int j = i - 17408;
        int row = j >> 10, cu = j & 1023;
        float2 v = *(const float2*)(W_out + (size_t)row * H_DIM + 256 + cu * 2);
        Wagg[j] = packbf(v.x, v.y);
    }
}

// ---- mega: per segment-half block; xp GEMM + score + out_part GEMM +
// register segment sum/max -> global partials (no atomics). 256 thr, 64-row chunks.
__global__ __launch_bounds__(256, 4) void mega_kernel(
        const float* __restrict__ x, const int* __restrict__ seg_start,
        const float* __restrict__ b_in, const float* __restrict__ b_a,
        const unsigned* __restrict__ Wb, const unsigned* __restrict__ Wa,
        const unsigned* __restrict__ Wo, unsigned short* __restrict__ out_part,
        float* __restrict__ psum, float* __restrict__ pmax) {
    __shared__ __align__(16) unsigned XP[64 * 68];   // xp chunk bf16 (u16 x136)
    __shared__ float scoref[64 * 8];
    unsigned short* XPs = (unsigned short*)XP;

    const int bb = blockIdx.x;                // 0..1023
    const int seg = bb >> 1, half = bb & 1;
    const int s0 = seg_start[seg], s1 = seg_start[seg + 1];
    const int cnt = s1 - s0;
    const int h = (cnt + 1) >> 1;
    const int hstart = s0 + half * h;
    const int hend = min(s1, hstart + h);

    const int t = threadIdx.x;
    const int w = t >> 6, l = t & 63, lr = l & 15, lk = l >> 4;
    const int a0 = t >> 6, f2 = t & 63;       // heads a0, a0+4; feats 2f2, 2f2+1

    // hoisted biases
    float binv[8];
#pragma unroll
    for (int nr = 0; nr < 8; ++nr) binv[nr] = b_in[nr * 16 + lr];
    const float ba = b_a[lr & 7];

    const f32x4 z4 = {0.f, 0.f, 0.f, 0.f};
    float sum0a = 0.f, sum1a = 0.f, sum2a = 0.f, sum3a = 0.f;
    float sum0b = 0.f, sum1b = 0.f, sum2b = 0.f, sum3b = 0.f;
    float mx0a = -INFINITY, mx1a = -INFINITY, mx2a = -INFINITY, mx3a = -INFINITY;
    float mx0b = -INFINITY, mx1b = -INFINITY, mx2b = -INFINITY, mx3b = -INFINITY;

    for (int c0 = hstart; c0 < hend; c0 += 64) {
        const int rc = min(64, hend - c0);
        const int arow = c0 + w * 16 + lr;
        const int arowc = min(arow, hend - 1);

        bf16x8 af[4];
#pragma unroll
        for (int ks = 0; ks < 4; ++ks) {
            const float4* xp4 = (const float4*)(x + (size_t)arowc * 128 + ks * 32 + lk * 8);
            af[ks] = pack8(xp4[0], xp4[1]);
        }
        // xp GEMM (B from global bf16)
        f32x4 acc[8];
#pragma unroll
        for (int nr = 0; nr < 8; ++nr) acc[nr] = z4;
#pragma unroll
        for (int ks = 0; ks < 4; ++ks)
#pragma unroll
            for (int nr = 0; nr < 8; ++nr) {
                bf16x8 bfrag = *(const bf16x8*)&Wb[(nr * 16 + lr) * 64 + ks * 16 + lk * 4];
                acc[nr] = __builtin_amdgcn_mfma_f32_16x16x32_bf16(af[ks], bfrag, acc[nr], 0, 0, 0);
            }
        // bias + XP write (own 16 rows)
#pragma unroll
        for (int nr = 0; nr < 8; ++nr)
#pragma unroll
            for (int r = 0; r < 4; ++r) {
                int row = w * 16 + lk * 4 + r;
                XPs[row * 136 + nr * 16 + lr] = f2bfu(((const float*)&acc[nr])[r] + binv[nr]);
            }
        // own XP rows as A-frags (same-wave write/read)
        bf16x8 xf[4];
#pragma unroll
        for (int ks = 0; ks < 4; ++ks)
            xf[ks] = *(const bf16x8*)&XPs[(w * 16 + lr) * 136 + ks * 32 + lk * 8];
        // score MFMA
        f32x4 sacc = z4;
#pragma unroll
        for (int ks = 0; ks < 4; ++ks) {
            bf16x8 bfrag = *(const bf16x8*)&Wa[lr * 64 + ks * 16 + lk * 4];
            sacc = __builtin_amdgcn_mfma_f32_16x16x32_bf16(xf[ks], bfrag, sacc, 0, 0, 0);
        }
        if (lr < A_HEADS) {
#pragma unroll
            for (int r = 0; r < 4; ++r) {
                int row = w * 16 + lk * 4 + r;
                scoref[row * 8 + lr] = __expf(-fabsf(((const float*)&sacc)[r] + ba));
            }
        }
        // out_part GEMM K=256 (x half + xp half)
        f32x4 aco[4];
#pragma unroll
        for (int nr = 0; nr < 4; ++nr) aco[nr] = z4;
#pragma unroll
        for (int ks = 0; ks < 4; ++ks)
#pragma unroll
            for (int nr = 0; nr < 4; ++nr) {
                bf16x8 b0 = *(const bf16x8*)&Wo[(nr * 16 + lr) * 128 + ks * 16 + lk * 4];
                aco[nr] = __builtin_amdgcn_mfma_f32_16x16x32_bf16(af[ks], b0, aco[nr], 0, 0, 0);
                bf16x8 b1 = *(const bf16x8*)&Wo[(nr * 16 + lr) * 128 + 64 + ks * 16 + lk * 4];
                aco[nr] = __builtin_amdgcn_mfma_f32_16x16x32_bf16(xf[ks], b1, aco[nr], 0, 0, 0);
            }
#pragma unroll
        for (int nr = 0; nr < 4; ++nr)
#pragma unroll
            for (int r = 0; r < 4; ++r) {
                int n = c0 + w * 16 + lk * 4 + r;
                if (n < hend)
                    out_part[(size_t)n * 64 + nr * 16 + lr] = f2bfu(((const float*)&aco[nr])[r]);
            }
        __syncthreads();   // XP + scoref visible

        // register agg: 2-way unrolled to break dep chains
        int i = 0;
        for (; i + 1 < rc; i += 2) {
            unsigned u0 = XP[i * 68 + f2];
            unsigned u1 = XP[(i + 1) * 68 + f2];
            float sA0 = scoref[i * 8 + a0],       sB0 = scoref[i * 8 + a0 + 4];
            float sA1 = scoref[(i + 1) * 8 + a0], sB1 = scoref[(i + 1) * 8 + a0 + 4];
            float x00 = bfl(u0), x01 = bfh(u0);
            float x10 = bfl(u1), x11 = bfh(u1);
            float e;
            e = sA0 * x00; sum0a += e; mx0a = fmaxf(mx0a, e);
            e = sA0 * x01; sum1a += e; mx1a = fmaxf(mx1a, e);
            e = sB0 * x00; sum2a += e; mx2a = fmaxf(mx2a, e);
            e = sB0 * x01; sum3a += e; mx3a = fmaxf(mx3a, e);
            e = sA1 * x10; sum0b += e; mx0b = fmaxf(mx0b, e);
            e = sA1 * x11; sum1b += e; mx1b = fmaxf(mx1b, e);
            e = sB1 * x10; sum2b += e; mx2b = fmaxf(mx2b, e);
            e = sB1 * x11; sum3b += e; mx3b = fmaxf(mx3b, e);
        }
        if (i < rc) {
            unsigned u0 = XP[i * 68 + f2];
            float sA0 = scoref[i * 8 + a0], sB0 = scoref[i * 8 + a0 + 4];
            float x00 = bfl(u0), x01 = bfh(u0);
            float e;
            e = sA0 * x00; sum0a += e; mx0a = fmaxf(mx0a, e);
            e = sA0 * x01; sum1a += e; mx1a = fmaxf(mx1a, e);
            e = sB0 * x00; sum2a += e; mx2a = fmaxf(mx2a, e);
            e = sB0 * x01; sum3a += e; mx3a = fmaxf(mx3a, e);
        }
        __syncthreads();   // before next chunk overwrites XP/scoref
    }

    // store partials (plain, coalesced float2)
    float* ps = psum + (size_t)bb * 1024;
    float* pm = pmax + (size_t)bb * 1024;
    *(float2*)&ps[a0 * 128 + 2 * f2]       = make_float2(sum0a + sum0b, sum1a + sum1b);
    *(float2*)&ps[(a0 + 4) * 128 + 2 * f2] = make_float2(sum2a + sum2b, sum3a + sum3b);
    *(float2*)&pm[a0 * 128 + 2 * f2]       = make_float2(fmaxf(mx0a, mx0b), fmaxf(mx1a, mx1b));
    *(float2*)&pm[(a0 + 4) * 128 + 2 * f2] = make_float2(fmaxf(mx2a, mx2b), fmaxf(mx3a, mx3b));
}

// ------- finalize: combine 2 halves, mean/max, project via bf16 Wagg --------
__global__ __launch_bounds__(256) void seg_final_kernel(
        const float* __restrict__ psum, const float* __restrict__ pmax,
        const int* __restrict__ seg_start, const unsigned* __restrict__ Wagg,
        const float* __restrict__ b_out, float* __restrict__ agg_proj) {
    __shared__ float agg[2048];
    const int b = blockIdx.x, t = threadIdx.x;
    const int cnt = seg_start[b + 1] - seg_start[b];
    const float inv = (cnt > 0) ? 1.f / (float)cnt : 0.f;
#pragma unroll
    for (int i = 0; i < 4; ++i) {
        int idx = i * 256 + t;
        float s = psum[(size_t)(2 * b) * 1024 + idx] + psum[(size_t)(2 * b + 1) * 1024 + idx];
        float m = fmaxf(pmax[(size_t)(2 * b) * 1024 + idx], pmax[(size_t)(2 * b + 1) * 1024 + idx]);
        int a = idx >> 7, f = idx & 127;
        agg[a * 256 + f] = s * inv;
        agg[a * 256 + 128 + f] = (cnt > 0) ? m : 0.f;
    }
    __syncthreads();
    const int wave = t >> 6, lane = t & 63;
#pragma unroll
    for (int i = 0; i < 16; ++i) {
        int o = wave * 16 + i;
        const unsigned* wrow = Wagg + (size_t)o * 1024;
        float partial = 0.f;
#pragma unroll
        for (int c = 0; c < 4; ++c) {
            int j4 = c * 256 + lane * 4;
            uint4 wv = *(const uint4*)&wrow[j4];
            const float* av = &agg[2 * j4];
            partial = fmaf(bfl(wv.x), av[0], partial);
            partial = fmaf(bfh(wv.x), av[1], partial);
            partial = fmaf(bfl(wv.y), av[2], partial);
            partial = fmaf(bfh(wv.y), av[3], partial);
            partial = fmaf(bfl(wv.z), av[4], partial);
            partial = fmaf(bfh(wv.z), av[5], partial);
            partial = fmaf(bfl(wv.w), av[6], partial);
            partial = fmaf(bfh(wv.w), av[7], partial);
        }
#pragma unroll
        for (int m = 1; m < 64; m <<= 1) partial += __shfl_xor(partial, m);
        if (lane == 0) agg_proj[b * D_OUTPUT + o] = partial + b_out[o];
    }
}

// -------- out = relu(out_part + agg_proj[batch]) — pure streaming -----------
__global__ __launch_bounds__(256) void out_final_kernel(
        const unsigned* __restrict__ out_part, const int* __restrict__ batch,
        const float* __restrict__ agg_proj, float* __restrict__ out) {
    int q = blockIdx.x * 256 + threadIdx.x;   // quad index: N*16 total
    if (q >= N_NODES * 16) return;
    int n = q >> 4, c4 = (q & 15) * 4;
    int bs = batch[n];
    uint2 v = *(const uint2*)(out_part + (size_t)n * 32 + (c4 >> 1));
    float4 ap = *(const float4*)(agg_proj + (size_t)bs * 64 + c4);
    float4 o;
    o.x = fmaxf(bfl(v.x) + ap.x, 0.f);
    o.y = fmaxf(bfh(v.x) + ap.y, 0.f);
    o.z = fmaxf(bfl(v.y) + ap.z, 0.f);
    o.w = fmaxf(bfh(v.y) + ap.w, 0.f);
    *(float4*)(out + (size_t)n * 64 + c4) = o;
}

extern "C" void kernel_launch(void* const* d_in, const int* in_sizes, int n_in,
                              void* d_out, int out_size, void* d_ws, size_t ws_size,
                              hipStream_t stream) {
    const float* x     = (const float*)d_in[0];
    const int*   batch = (const int*)d_in[1];
    const float* W_in  = (const float*)d_in[3];
    const float* b_in  = (const float*)d_in[4];
    const float* W_a   = (const float*)d_in[5];
    const float* b_a   = (const float*)d_in[6];
    const float* W_out = (const float*)d_in[7];
    const float* b_out = (const float*)d_in[8];
    float* out = (float*)d_out;

    float* agg_proj = (float*)d_ws;                          // 32768 f32
    int* seg_start  = (int*)(agg_proj + 32768);              // 520 ints
    unsigned* Wb    = (unsigned*)(seg_start + 520);          // 8192
    unsigned* Wa    = Wb + 8192;                             // 1024
    unsigned* Wo    = Wa + 1024;                             // 8192
    unsigned* Wagg  = Wo + 8192;                             // 65536
    float* psum     = (float*)(Wagg + 65536);                // 1024*1024
    float* pmax     = psum + 1048576;                        // 1024*1024
    unsigned short* out_part = (unsigned short*)(pmax + 1048576); // N*64 u16
    unsigned* out_part_u32 = (unsigned*)out_part;

    seg_bounds_kernel<<<1, 1024, 0, stream>>>(batch, N_NODES, seg_start);
    wconv_kernel<<<324, 256, 0, stream>>>(W_in, W_a, W_out, Wb, Wa, Wo, Wagg);
    mega_kernel<<<2 * B_SEGS, 256, 0, stream>>>(
        x, seg_start, b_in, b_a, Wb, Wa, Wo, out_part, psum, pmax);
    seg_final_kernel<<<B_SEGS, 256, 0, stream>>>(
        psum, pmax, seg_start, Wagg, b_out, agg_proj);
    out_final_kernel<<<(N_NODES * 16 + 255) / 256, 256, 0, stream>>>(
        out_part_u32, batch, agg_proj, out);
}

// Round 7
// 93.975 us; speedup vs baseline: 2.3943x; 2.3943x over previous
//
#include <hip/hip_runtime.h>
#include <math.h>

#define N_NODES 100000
#define D_INPUT 128
#define FDIM 128
#define A_HEADS 8
#define B_SEGS 512
#define D_OUTPUT 64
#define H_DIM 2304

typedef __attribute__((ext_vector_type(8))) __bf16 bf16x8;
typedef __attribute__((ext_vector_type(4))) float f32x4;

static __device__ inline unsigned short f2bfu(float f) {
    unsigned u = __builtin_bit_cast(unsigned, f);
    u += 0x7fffu + ((u >> 16) & 1u);
    return (unsigned short)(u >> 16);
}
static __device__ inline unsigned packbf(float a, float b) {
    return (unsigned)f2bfu(a) | ((unsigned)f2bfu(b) << 16);
}
static __device__ inline float bfl(unsigned u) {
    unsigned x = u << 16; return __builtin_bit_cast(float, x);
}
static __device__ inline float bfh(unsigned u) {
    unsigned x = u & 0xffff0000u; return __builtin_bit_cast(float, x);
}
static __device__ inline bf16x8 pack8(float4 a, float4 b) {
    union { unsigned u[4]; bf16x8 v; } r;
    r.u[0] = packbf(a.x, a.y); r.u[1] = packbf(a.z, a.w);
    r.u[2] = packbf(b.x, b.y); r.u[3] = packbf(b.z, b.w);
    return r.v;
}

// ---------------- segment boundaries (batch is sorted) ----------------
__global__ void seg_bounds_kernel(const int* __restrict__ batch, int n,
                                  int* __restrict__ seg_start) {
    int b = threadIdx.x;
    if (b > B_SEGS) return;
    int lo = 0, hi = n;
    while (lo < hi) {
        int mid = (lo + hi) >> 1;
        if (batch[mid] < b) lo = mid + 1; else hi = mid;
    }
    seg_start[b] = lo;
}

// ------- one-time weight conversion fp32 -> bf16 (packed u32), global -------
// Wb [128][64]u32, Wa [16][64]u32 (rows 8..15 zero), Wo [64][128]u32 (K 0..255),
// Wagg [64][1024]u32 (W_out cols 256..2303)
__global__ __launch_bounds__(256) void wconv_kernel(
        const float* __restrict__ W_in, const float* __restrict__ W_a,
        const float* __restrict__ W_out, unsigned* __restrict__ Wb,
        unsigned* __restrict__ Wa, unsigned* __restrict__ Wo,
        unsigned* __restrict__ Wagg) {
    int i = blockIdx.x * 256 + threadIdx.x;
    if (i < 8192) {
        float2 v = *(const float2*)(W_in + (size_t)i * 2);
        Wb[i] = packbf(v.x, v.y);
    } else if (i < 9216) {
        int j = i - 8192;
        if (j < 512) {
            float2 v = *(const float2*)(W_a + (size_t)j * 2);
            Wa[j] = packbf(v.x, v.y);
        } else Wa[j] = 0u;
    } else if (i < 17408) {
        int j = i - 9216;
        int row = j >> 7, cu = j & 127;
        float2 v = *(const float2*)(W_out + (size_t)row * H_DIM + cu * 2);
        Wo[j] = packbf(v.x, v.y);
    } else if (i < 82944) {
        int j = i - 17408;
        int row = j >> 10, cu = j & 1023;
        float2 v = *(const float2*)(W_out + (size_t)row * H_DIM + 256 + cu * 2);
        Wagg[j] = packbf(v.x, v.y);
    }
}

// ---- segment-major mega: one block per segment, 512 threads, fully fused ----
__global__ __launch_bounds__(512, 4) void mega_kernel(
        const float* __restrict__ x, const int* __restrict__ seg_start,
        const float* __restrict__ b_in, const float* __restrict__ b_a,
        const float* __restrict__ b_out, const unsigned* __restrict__ Wb,
        const unsigned* __restrict__ Wa, const unsigned* __restrict__ Wo,
        const unsigned* __restrict__ Wagg, unsigned* __restrict__ out_part_u32,
        float* __restrict__ out) {
    __shared__ __align__(16) unsigned WbL[128 * 68];   // W_in bf16
    __shared__ __align__(16) unsigned WaL[16 * 68];    // W_a bf16 (8..15 zero)
    __shared__ __align__(16) unsigned XP[128 * 68];    // xp chunk bf16 / agg f32
    __shared__ float scoref[128 * 8];
    __shared__ float projL[64];
    unsigned short* XPs = (unsigned short*)XP;
    float* XPf = (float*)XP;
    unsigned short* opart16 = (unsigned short*)out_part_u32;

    const int b = blockIdx.x;
    const int s0 = seg_start[b], s1 = seg_start[b + 1];
    const int cnt = s1 - s0;
    if (cnt == 0) return;
    const int t = threadIdx.x;

    // stage Wb (2048 uint4) + Wa (256 uint4) from pre-converted bf16 global
    {
        const uint4* src = (const uint4*)Wb;
#pragma unroll
        for (int i = 0; i < 4; ++i) {
            int idx = i * 512 + t;
            int row = idx >> 4, c4 = idx & 15;
            *(uint4*)&WbL[row * 68 + c4 * 4] = src[idx];
        }
        if (t < 256) {
            const uint4* sa = (const uint4*)Wa;
            int row = t >> 4, c4 = t & 15;
            *(uint4*)&WaL[row * 68 + c4 * 4] = sa[t];
        }
    }
    __syncthreads();

    const int w = t >> 6, l = t & 63, lr = l & 15, lk = l >> 4;
    const int a0 = w, f2 = l;     // agg ownership: head w, feature pair 2l,2l+1

    float binv[8];
#pragma unroll
    for (int nr = 0; nr < 8; ++nr) binv[nr] = b_in[nr * 16 + lr];
    const float ba = b_a[lr & 7];

    const f32x4 z4 = {0.f, 0.f, 0.f, 0.f};
    float sum0 = 0.f, sum1 = 0.f, mx0 = -INFINITY, mx1 = -INFINITY;

    for (int c0 = s0; c0 < s1; c0 += 128) {
        const int rc = min(128, s1 - c0);
        const int arow = c0 + w * 16 + lr;
        const int arowc = min(arow, s1 - 1);

        bf16x8 af[4];
#pragma unroll
        for (int ks = 0; ks < 4; ++ks) {
            const float4* xp4 = (const float4*)(x + (size_t)arowc * 128 + ks * 32 + lk * 8);
            af[ks] = pack8(xp4[0], xp4[1]);
        }
        // xp GEMM (B from LDS)
        f32x4 acc[8];
#pragma unroll
        for (int nr = 0; nr < 8; ++nr) acc[nr] = z4;
#pragma unroll
        for (int ks = 0; ks < 4; ++ks)
#pragma unroll
            for (int nr = 0; nr < 8; ++nr) {
                bf16x8 bfrag = *(const bf16x8*)&WbL[(nr * 16 + lr) * 68 + ks * 16 + lk * 4];
                acc[nr] = __builtin_amdgcn_mfma_f32_16x16x32_bf16(af[ks], bfrag, acc[nr], 0, 0, 0);
            }
        // bias + XP write (own 16 rows)
#pragma unroll
        for (int nr = 0; nr < 8; ++nr)
#pragma unroll
            for (int r = 0; r < 4; ++r) {
                int row = w * 16 + lk * 4 + r;
                XPs[row * 136 + nr * 16 + lr] = f2bfu(((const float*)&acc[nr])[r] + binv[nr]);
            }
        // own XP rows back as A-frags (same-wave write/read)
        bf16x8 xf[4];
#pragma unroll
        for (int ks = 0; ks < 4; ++ks)
            xf[ks] = *(const bf16x8*)&XPs[(w * 16 + lr) * 136 + ks * 32 + lk * 8];
        // score MFMA
        f32x4 sacc = z4;
#pragma unroll
        for (int ks = 0; ks < 4; ++ks) {
            bf16x8 bfrag = *(const bf16x8*)&WaL[lr * 68 + ks * 16 + lk * 4];
            sacc = __builtin_amdgcn_mfma_f32_16x16x32_bf16(xf[ks], bfrag, sacc, 0, 0, 0);
        }
        if (lr < A_HEADS) {
#pragma unroll
            for (int r = 0; r < 4; ++r) {
                int row = w * 16 + lk * 4 + r;
                scoref[row * 8 + lr] = __expf(-fabsf(((const float*)&sacc)[r] + ba));
            }
        }
        // out_part GEMM K=256 (B-frags from global bf16 Wo, L2-hot)
        f32x4 aco[4];
#pragma unroll
        for (int nr = 0; nr < 4; ++nr) aco[nr] = z4;
#pragma unroll
        for (int ks = 0; ks < 4; ++ks)
#pragma unroll
            for (int nr = 0; nr < 4; ++nr) {
                bf16x8 b0 = *(const bf16x8*)&Wo[(nr * 16 + lr) * 128 + ks * 16 + lk * 4];
                aco[nr] = __builtin_amdgcn_mfma_f32_16x16x32_bf16(af[ks], b0, aco[nr], 0, 0, 0);
                bf16x8 b1 = *(const bf16x8*)&Wo[(nr * 16 + lr) * 128 + 64 + ks * 16 + lk * 4];
                aco[nr] = __builtin_amdgcn_mfma_f32_16x16x32_bf16(xf[ks], b1, aco[nr], 0, 0, 0);
            }
#pragma unroll
        for (int nr = 0; nr < 4; ++nr)
#pragma unroll
            for (int r = 0; r < 4; ++r) {
                int n = c0 + w * 16 + lk * 4 + r;
                if (n < s1)
                    opart16[(size_t)n * 64 + nr * 16 + lr] = f2bfu(((const float*)&aco[nr])[r]);
            }
        __syncthreads();   // XP + scoref visible to all waves

        // register agg: thread = (head a0, feat pair 2*f2,2*f2+1)
        for (int i = 0; i < rc; ++i) {
            unsigned u = XP[i * 68 + f2];
            float sa = scoref[i * 8 + a0];
            float e0 = sa * bfl(u), e1 = sa * bfh(u);
            sum0 += e0; sum1 += e1;
            mx0 = fmaxf(mx0, e0); mx1 = fmaxf(mx1, e1);
        }
        __syncthreads();   // before next chunk overwrites XP/scoref
    }

    // ---- agg vector into XPf ----
    const float inv = 1.f / (float)cnt;
    XPf[a0 * 256 + 2 * f2]           = sum0 * inv;
    XPf[a0 * 256 + 2 * f2 + 1]       = sum1 * inv;
    XPf[a0 * 256 + 128 + 2 * f2]     = mx0;
    XPf[a0 * 256 + 128 + 2 * f2 + 1] = mx1;
    __syncthreads();

    // ---- projection via bf16 Wagg: wave w -> outputs w*8..w*8+7 ----
#pragma unroll
    for (int i = 0; i < 8; ++i) {
        int o = w * 8 + i;
        const unsigned* wrow = Wagg + (size_t)o * 1024;
        float partial = 0.f;
#pragma unroll
        for (int c = 0; c < 4; ++c) {
            int j4 = c * 256 + l * 4;
            uint4 wv = *(const uint4*)&wrow[j4];
            const float* av = &XPf[2 * j4];
            partial = fmaf(bfl(wv.x), av[0], partial);
            partial = fmaf(bfh(wv.x), av[1], partial);
            partial = fmaf(bfl(wv.y), av[2], partial);
            partial = fmaf(bfh(wv.y), av[3], partial);
            partial = fmaf(bfl(wv.z), av[4], partial);
            partial = fmaf(bfh(wv.z), av[5], partial);
            partial = fmaf(bfl(wv.w), av[6], partial);
            partial = fmaf(bfh(wv.w), av[7], partial);
        }
#pragma unroll
        for (int m = 1; m < 64; m <<= 1) partial += __shfl_xor(partial, m);
        if (l == 0) projL[o] = partial + b_out[o];
    }
    __threadfence_block();
    __syncthreads();

    // ---- final: out = relu(out_part + projL) for own rows ----
    const int rr = t >> 3, cg = t & 7;
    float p[8];
#pragma unroll
    for (int j = 0; j < 8; ++j) p[j] = projL[cg * 8 + j];
    for (int r0 = s0; r0 < s1; r0 += 64) {
        int row = r0 + rr;
        if (row < s1) {
            uint4 v = *(const uint4*)&out_part_u32[(size_t)row * 32 + cg * 4];
            float4 o0, o1;
            o0.x = fmaxf(bfl(v.x) + p[0], 0.f);
            o0.y = fmaxf(bfh(v.x) + p[1], 0.f);
            o0.z = fmaxf(bfl(v.y) + p[2], 0.f);
            o0.w = fmaxf(bfh(v.y) + p[3], 0.f);
            o1.x = fmaxf(bfl(v.z) + p[4], 0.f);
            o1.y = fmaxf(bfh(v.z) + p[5], 0.f);
            o1.z = fmaxf(bfl(v.w) + p[6], 0.f);
            o1.w = fmaxf(bfh(v.w) + p[7], 0.f);
            *(float4*)&out[(size_t)row * 64 + cg * 8] = o0;
            *(float4*)&out[(size_t)row * 64 + cg * 8 + 4] = o1;
        }
    }
}

extern "C" void kernel_launch(void* const* d_in, const int* in_sizes, int n_in,
                              void* d_out, int out_size, void* d_ws, size_t ws_size,
                              hipStream_t stream) {
    const float* x     = (const float*)d_in[0];
    const int*   batch = (const int*)d_in[1];
    const float* W_in  = (const float*)d_in[3];
    const float* b_in  = (const float*)d_in[4];
    const float* W_a   = (const float*)d_in[5];
    const float* b_a   = (const float*)d_in[6];
    const float* W_out = (const float*)d_in[7];
    const float* b_out = (const float*)d_in[8];
    float* out = (float*)d_out;

    int* seg_start  = (int*)d_ws;                            // 520 ints
    unsigned* Wb    = (unsigned*)(seg_start + 520);          // 8192
    unsigned* Wa    = Wb + 8192;                             // 1024
    unsigned* Wo    = Wa + 1024;                             // 8192
    unsigned* Wagg  = Wo + 8192;                             // 65536
    unsigned* out_part_u32 = Wagg + 65536;                   // N*32 u32

    seg_bounds_kernel<<<1, 1024, 0, stream>>>(batch, N_NODES, seg_start);
    wconv_kernel<<<324, 256, 0, stream>>>(W_in, W_a, W_out, Wb, Wa, Wo, Wagg);
    mega_kernel<<<B_SEGS, 512, 0, stream>>>(
        x, seg_start, b_in, b_a, b_out, Wb, Wa, Wo, Wagg, out_part_u32, out);
}

// Round 8
// 79.653 us; speedup vs baseline: 2.8249x; 1.1798x over previous
//
#include <hip/hip_runtime.h>
#include <math.h>

#define N_NODES 100000
#define D_INPUT 128
#define FDIM 128
#define A_HEADS 8
#define B_SEGS 512
#define D_OUTPUT 64
#define H_DIM 2304

typedef __attribute__((ext_vector_type(8))) __bf16 bf16x8;
typedef __attribute__((ext_vector_type(4))) float f32x4;

static __device__ inline unsigned short f2bfu(float f) {
    unsigned u = __builtin_bit_cast(unsigned, f);
    u += 0x7fffu + ((u >> 16) & 1u);
    return (unsigned short)(u >> 16);
}
static __device__ inline unsigned packbf(float a, float b) {
    return (unsigned)f2bfu(a) | ((unsigned)f2bfu(b) << 16);
}
static __device__ inline float bfl(unsigned u) {
    unsigned x = u << 16; return __builtin_bit_cast(float, x);
}
static __device__ inline float bfh(unsigned u) {
    unsigned x = u & 0xffff0000u; return __builtin_bit_cast(float, x);
}
static __device__ inline bf16x8 pack8(float4 a, float4 b) {
    union { unsigned u[4]; bf16x8 v; } r;
    r.u[0] = packbf(a.x, a.y); r.u[1] = packbf(a.z, a.w);
    r.u[2] = packbf(b.x, b.y); r.u[3] = packbf(b.z, b.w);
    return r.v;
}

// ---------------- segment boundaries (batch is sorted) ----------------
__global__ void seg_bounds_kernel(const int* __restrict__ batch, int n,
                                  int* __restrict__ seg_start) {
    int b = threadIdx.x;
    if (b > B_SEGS) return;
    int lo = 0, hi = n;
    while (lo < hi) {
        int mid = (lo + hi) >> 1;
        if (batch[mid] < b) lo = mid + 1; else hi = mid;
    }
    seg_start[b] = lo;
}

// ------- one-time weight conversion fp32 -> bf16 (packed u32), global -------
// Wb [128][64]u32, Wa [16][64]u32 (rows 8..15 zero), Wo [64][128]u32 (K 0..255),
// Wagg [64][1024]u32 (W_out cols 256..2303)
__global__ __launch_bounds__(256) void wconv_kernel(
        const float* __restrict__ W_in, const float* __restrict__ W_a,
        const float* __restrict__ W_out, unsigned* __restrict__ Wb,
        unsigned* __restrict__ Wa, unsigned* __restrict__ Wo,
        unsigned* __restrict__ Wagg) {
    int i = blockIdx.x * 256 + threadIdx.x;
    if (i < 8192) {
        float2 v = *(const float2*)(W_in + (size_t)i * 2);
        Wb[i] = packbf(v.x, v.y);
    } else if (i < 9216) {
        int j = i - 8192;
        if (j < 512) {
            float2 v = *(const float2*)(W_a + (size_t)j * 2);
            Wa[j] = packbf(v.x, v.y);
        } else Wa[j] = 0u;
    } else if (i < 17408) {
        int j = i - 9216;
        int row = j >> 7, cu = j & 127;
        float2 v = *(const float2*)(W_out + (size_t)row * H_DIM + cu * 2);
        Wo[j] = packbf(v.x, v.y);
    } else if (i < 82944) {
        int j = i - 17408;
        int row = j >> 10, cu = j & 1023;
        float2 v = *(const float2*)(W_out + (size_t)row * H_DIM + 256 + cu * 2);
        Wagg[j] = packbf(v.x, v.y);
    }
}

// ---- segment-major mega: one block per segment, 512 threads, fully fused ----
// NOTE: min-waves-per-EU floor of 4 forces VGPR=64 -> accumulator spill
// (R6/R7 regressions: +200MB symmetric FETCH/WRITE scratch traffic). Keep 2.
__global__ __launch_bounds__(512, 2) void mega_kernel(
        const float* __restrict__ x, const int* __restrict__ seg_start,
        const float* __restrict__ b_in, const float* __restrict__ b_a,
        const float* __restrict__ b_out, const unsigned* __restrict__ Wb,
        const unsigned* __restrict__ Wa, const unsigned* __restrict__ Wo,
        const unsigned* __restrict__ Wagg, unsigned* __restrict__ out_part_u32,
        float* __restrict__ out) {
    __shared__ __align__(16) unsigned WbL[128 * 68];   // W_in bf16
    __shared__ __align__(16) unsigned WaL[16 * 68];    // W_a bf16 (8..15 zero)
    __shared__ __align__(16) unsigned XP[128 * 68];    // xp chunk bf16 / agg f32
    __shared__ float scoref[128 * 8];
    __shared__ float projL[64];
    unsigned short* XPs = (unsigned short*)XP;
    float* XPf = (float*)XP;
    unsigned short* opart16 = (unsigned short*)out_part_u32;

    const int b = blockIdx.x;
    const int s0 = seg_start[b], s1 = seg_start[b + 1];
    const int cnt = s1 - s0;
    if (cnt == 0) return;
    const int t = threadIdx.x;

    // stage Wb (2048 uint4) + Wa (256 uint4) from pre-converted bf16 global
    {
        const uint4* src = (const uint4*)Wb;
#pragma unroll
        for (int i = 0; i < 4; ++i) {
            int idx = i * 512 + t;
            int row = idx >> 4, c4 = idx & 15;
            *(uint4*)&WbL[row * 68 + c4 * 4] = src[idx];
        }
        if (t < 256) {
            const uint4* sa = (const uint4*)Wa;
            int row = t >> 4, c4 = t & 15;
            *(uint4*)&WaL[row * 68 + c4 * 4] = sa[t];
        }
    }
    __syncthreads();

    const int w = t >> 6, l = t & 63, lr = l & 15, lk = l >> 4;
    const int a0 = w, f2 = l;     // agg ownership: head w, feature pair 2l,2l+1

    float binv[8];
#pragma unroll
    for (int nr = 0; nr < 8; ++nr) binv[nr] = b_in[nr * 16 + lr];
    const float ba = b_a[lr & 7];

    const f32x4 z4 = {0.f, 0.f, 0.f, 0.f};
    float sum0 = 0.f, sum1 = 0.f, mx0 = -INFINITY, mx1 = -INFINITY;

    for (int c0 = s0; c0 < s1; c0 += 128) {
        const int rc = min(128, s1 - c0);
        const int arow = c0 + w * 16 + lr;
        const int arowc = min(arow, s1 - 1);

        bf16x8 af[4];
#pragma unroll
        for (int ks = 0; ks < 4; ++ks) {
            const float4* xp4 = (const float4*)(x + (size_t)arowc * 128 + ks * 32 + lk * 8);
            af[ks] = pack8(xp4[0], xp4[1]);
        }
        // xp GEMM (B from LDS)
        f32x4 acc[8];
#pragma unroll
        for (int nr = 0; nr < 8; ++nr) acc[nr] = z4;
#pragma unroll
        for (int ks = 0; ks < 4; ++ks)
#pragma unroll
            for (int nr = 0; nr < 8; ++nr) {
                bf16x8 bfrag = *(const bf16x8*)&WbL[(nr * 16 + lr) * 68 + ks * 16 + lk * 4];
                acc[nr] = __builtin_amdgcn_mfma_f32_16x16x32_bf16(af[ks], bfrag, acc[nr], 0, 0, 0);
            }
        // bias + XP write (own 16 rows)
#pragma unroll
        for (int nr = 0; nr < 8; ++nr)
#pragma unroll
            for (int r = 0; r < 4; ++r) {
                int row = w * 16 + lk * 4 + r;
                XPs[row * 136 + nr * 16 + lr] = f2bfu(((const float*)&acc[nr])[r] + binv[nr]);
            }
        // own XP rows back as A-frags (same-wave write/read)
        bf16x8 xf[4];
#pragma unroll
        for (int ks = 0; ks < 4; ++ks)
            xf[ks] = *(const bf16x8*)&XPs[(w * 16 + lr) * 136 + ks * 32 + lk * 8];
        // score MFMA
        f32x4 sacc = z4;
#pragma unroll
        for (int ks = 0; ks < 4; ++ks) {
            bf16x8 bfrag = *(const bf16x8*)&WaL[lr * 68 + ks * 16 + lk * 4];
            sacc = __builtin_amdgcn_mfma_f32_16x16x32_bf16(xf[ks], bfrag, sacc, 0, 0, 0);
        }
        if (lr < A_HEADS) {
#pragma unroll
            for (int r = 0; r < 4; ++r) {
                int row = w * 16 + lk * 4 + r;
                scoref[row * 8 + lr] = __expf(-fabsf(((const float*)&sacc)[r] + ba));
            }
        }
        // out_part GEMM K=256 (B-frags from global bf16 Wo, L2-hot)
        f32x4 aco[4];
#pragma unroll
        for (int nr = 0; nr < 4; ++nr) aco[nr] = z4;
#pragma unroll
        for (int ks = 0; ks < 4; ++ks)
#pragma unroll
            for (int nr = 0; nr < 4; ++nr) {
                bf16x8 b0 = *(const bf16x8*)&Wo[(nr * 16 + lr) * 128 + ks * 16 + lk * 4];
                aco[nr] = __builtin_amdgcn_mfma_f32_16x16x32_bf16(af[ks], b0, aco[nr], 0, 0, 0);
                bf16x8 b1 = *(const bf16x8*)&Wo[(nr * 16 + lr) * 128 + 64 + ks * 16 + lk * 4];
                aco[nr] = __builtin_amdgcn_mfma_f32_16x16x32_bf16(xf[ks], b1, aco[nr], 0, 0, 0);
            }
#pragma unroll
        for (int nr = 0; nr < 4; ++nr)
#pragma unroll
            for (int r = 0; r < 4; ++r) {
                int n = c0 + w * 16 + lk * 4 + r;
                if (n < s1)
                    opart16[(size_t)n * 64 + nr * 16 + lr] = f2bfu(((const float*)&aco[nr])[r]);
            }
        __syncthreads();   // XP + scoref visible to all waves

        // register agg: thread = (head a0, feat pair 2*f2,2*f2+1)
        for (int i = 0; i < rc; ++i) {
            unsigned u = XP[i * 68 + f2];
            float sa = scoref[i * 8 + a0];
            float e0 = sa * bfl(u), e1 = sa * bfh(u);
            sum0 += e0; sum1 += e1;
            mx0 = fmaxf(mx0, e0); mx1 = fmaxf(mx1, e1);
        }
        __syncthreads();   // before next chunk overwrites XP/scoref
    }

    // ---- agg vector into XPf ----
    const float inv = 1.f / (float)cnt;
    XPf[a0 * 256 + 2 * f2]           = sum0 * inv;
    XPf[a0 * 256 + 2 * f2 + 1]       = sum1 * inv;
    XPf[a0 * 256 + 128 + 2 * f2]     = mx0;
    XPf[a0 * 256 + 128 + 2 * f2 + 1] = mx1;
    __syncthreads();

    // ---- projection via bf16 Wagg: wave w -> outputs w*8..w*8+7 ----
#pragma unroll
    for (int i = 0; i < 8; ++i) {
        int o = w * 8 + i;
        const unsigned* wrow = Wagg + (size_t)o * 1024;
        float partial = 0.f;
#pragma unroll
        for (int c = 0; c < 4; ++c) {
            int j4 = c * 256 + l * 4;
            uint4 wv = *(const uint4*)&wrow[j4];
            const float* av = &XPf[2 * j4];
            partial = fmaf(bfl(wv.x), av[0], partial);
            partial = fmaf(bfh(wv.x), av[1], partial);
            partial = fmaf(bfl(wv.y), av[2], partial);
            partial = fmaf(bfh(wv.y), av[3], partial);
            partial = fmaf(bfl(wv.z), av[4], partial);
            partial = fmaf(bfh(wv.z), av[5], partial);
            partial = fmaf(bfl(wv.w), av[6], partial);
            partial = fmaf(bfh(wv.w), av[7], partial);
        }
#pragma unroll
        for (int m = 1; m < 64; m <<= 1) partial += __shfl_xor(partial, m);
        if (l == 0) projL[o] = partial + b_out[o];
    }
    __syncthreads();

    // ---- final: out = relu(out_part + projL) for own rows ----
    const int rr = t >> 3, cg = t & 7;
    float p[8];
#pragma unroll
    for (int j = 0; j < 8; ++j) p[j] = projL[cg * 8 + j];
    for (int r0 = s0; r0 < s1; r0 += 64) {
        int row = r0 + rr;
        if (row < s1) {
            uint4 v = *(const uint4*)&out_part_u32[(size_t)row * 32 + cg * 4];
            float4 o0, o1;
            o0.x = fmaxf(bfl(v.x) + p[0], 0.f);
            o0.y = fmaxf(bfh(v.x) + p[1], 0.f);
            o0.z = fmaxf(bfl(v.y) + p[2], 0.f);
            o0.w = fmaxf(bfh(v.y) + p[3], 0.f);
            o1.x = fmaxf(bfl(v.z) + p[4], 0.f);
            o1.y = fmaxf(bfh(v.z) + p[5], 0.f);
            o1.z = fmaxf(bfl(v.w) + p[6], 0.f);
            o1.w = fmaxf(bfh(v.w) + p[7], 0.f);
            *(float4*)&out[(size_t)row * 64 + cg * 8] = o0;
            *(float4*)&out[(size_t)row * 64 + cg * 8 + 4] = o1;
        }
    }
}

extern "C" void kernel_launch(void* const* d_in, const int* in_sizes, int n_in,
                              void* d_out, int out_size, void* d_ws, size_t ws_size,
                              hipStream_t stream) {
    const float* x     = (const float*)d_in[0];
    const int*   batch = (const int*)d_in[1];
    const float* W_in  = (const float*)d_in[3];
    const float* b_in  = (const float*)d_in[4];
    const float* W_a   = (const float*)d_in[5];
    const float* b_a   = (const float*)d_in[6];
    const float* W_out = (const float*)d_in[7];
    const float* b_out = (const float*)d_in[8];
    float* out = (float*)d_out;

    int* seg_start  = (int*)d_ws;                            // 520 ints
    unsigned* Wb    = (unsigned*)(seg_start + 520);          // 8192
    unsigned* Wa    = Wb + 8192;                             // 1024
    unsigned* Wo    = Wa + 1024;                             // 8192
    unsigned* Wagg  = Wo + 8192;                             // 65536
    unsigned* out_part_u32 = Wagg + 65536;                   // N*32 u32

    seg_bounds_kernel<<<1, 1024, 0, stream>>>(batch, N_NODES, seg_start);
    wconv_kernel<<<324, 256, 0, stream>>>(W_in, W_a, W_out, Wb, Wa, Wo, Wagg);
    mega_kernel<<<B_SEGS, 512, 0, stream>>>(
        x, seg_start, b_in, b_a, b_out, Wb, Wa, Wo, Wagg, out_part_u32, out);
}

// Round 9
// 77.332 us; speedup vs baseline: 2.9097x; 1.0300x over previous
//
#include <hip/hip_runtime.h>
#include <math.h>

#define N_NODES 100000
#define D_INPUT 128
#define FDIM 128
#define A_HEADS 8
#define B_SEGS 512
#define D_OUTPUT 64
#define H_DIM 2304

typedef __attribute__((ext_vector_type(8))) __bf16 bf16x8;
typedef __attribute__((ext_vector_type(4))) float f32x4;

static __device__ inline unsigned short f2bfu(float f) {
    unsigned u = __builtin_bit_cast(unsigned, f);
    u += 0x7fffu + ((u >> 16) & 1u);
    return (unsigned short)(u >> 16);
}
static __device__ inline unsigned packbf(float a, float b) {
    return (unsigned)f2bfu(a) | ((unsigned)f2bfu(b) << 16);
}
static __device__ inline float bfl(unsigned u) {
    unsigned x = u << 16; return __builtin_bit_cast(float, x);
}
static __device__ inline float bfh(unsigned u) {
    unsigned x = u & 0xffff0000u; return __builtin_bit_cast(float, x);
}
static __device__ inline bf16x8 pack8(float4 a, float4 b) {
    union { unsigned u[4]; bf16x8 v; } r;
    r.u[0] = packbf(a.x, a.y); r.u[1] = packbf(a.z, a.w);
    r.u[2] = packbf(b.x, b.y); r.u[3] = packbf(b.z, b.w);
    return r.v;
}

// ---------------- segment boundaries (batch is sorted) ----------------
__global__ void seg_bounds_kernel(const int* __restrict__ batch, int n,
                                  int* __restrict__ seg_start) {
    int b = threadIdx.x;
    if (b > B_SEGS) return;
    int lo = 0, hi = n;
    while (lo < hi) {
        int mid = (lo + hi) >> 1;
        if (batch[mid] < b) lo = mid + 1; else hi = mid;
    }
    seg_start[b] = lo;
}

// ------- one-time weight conversion fp32 -> bf16 (packed u32), global -------
__global__ __launch_bounds__(256) void wconv_kernel(
        const float* __restrict__ W_in, const float* __restrict__ W_a,
        const float* __restrict__ W_out, unsigned* __restrict__ Wb,
        unsigned* __restrict__ Wa, unsigned* __restrict__ Wo,
        unsigned* __restrict__ Wagg) {
    int i = blockIdx.x * 256 + threadIdx.x;
    if (i < 8192) {
        float2 v = *(const float2*)(W_in + (size_t)i * 2);
        Wb[i] = packbf(v.x, v.y);
    } else if (i < 9216) {
        int j = i - 8192;
        if (j < 512) {
            float2 v = *(const float2*)(W_a + (size_t)j * 2);
            Wa[j] = packbf(v.x, v.y);
        } else Wa[j] = 0u;
    } else if (i < 17408) {
        int j = i - 9216;
        int row = j >> 7, cu = j & 127;
        float2 v = *(const float2*)(W_out + (size_t)row * H_DIM + cu * 2);
        Wo[j] = packbf(v.x, v.y);
    } else if (i < 82944) {
        int j = i - 17408;
        int row = j >> 10, cu = j & 1023;
        float2 v = *(const float2*)(W_out + (size_t)row * H_DIM + 256 + cu * 2);
        Wagg[j] = packbf(v.x, v.y);
    }
}

// ---- segment-major mega: one block per segment, 512 threads, fully fused ----
// NOTE: min-waves floor of 4 forces VGPR=64 -> accumulator spill (R6/R7:
// +200MB symmetric FETCH/WRITE scratch traffic). Keep the floor at 2 and
// let actual usage determine occupancy.
__global__ __launch_bounds__(512, 2) void mega_kernel(
        const float* __restrict__ x, const int* __restrict__ seg_start,
        const float* __restrict__ b_in, const float* __restrict__ b_a,
        const float* __restrict__ b_out, const unsigned* __restrict__ Wb,
        const unsigned* __restrict__ Wa, const unsigned* __restrict__ Wo,
        const unsigned* __restrict__ Wagg, unsigned* __restrict__ out_part_u32,
        float* __restrict__ out) {
    __shared__ __align__(16) unsigned WbL[128 * 68];   // W_in bf16
    __shared__ __align__(16) unsigned WaL[16 * 68];    // W_a bf16 (8..15 zero)
    __shared__ __align__(16) unsigned XP[128 * 68];    // xp chunk bf16 / agg f32
    __shared__ float scoref[128 * 8];
    __shared__ float projL[64];
    unsigned short* XPs = (unsigned short*)XP;
    float* XPf = (float*)XP;
    unsigned short* opart16 = (unsigned short*)out_part_u32;

    const int b = blockIdx.x;
    const int s0 = seg_start[b], s1 = seg_start[b + 1];
    const int cnt = s1 - s0;
    if (cnt == 0) return;
    const int t = threadIdx.x;

    // stage Wb (2048 uint4) + Wa (256 uint4) from pre-converted bf16 global
    {
        const uint4* src = (const uint4*)Wb;
#pragma unroll
        for (int i = 0; i < 4; ++i) {
            int idx = i * 512 + t;
            int row = idx >> 4, c4 = idx & 15;
            *(uint4*)&WbL[row * 68 + c4 * 4] = src[idx];
        }
        if (t < 256) {
            const uint4* sa = (const uint4*)Wa;
            int row = t >> 4, c4 = t & 15;
            *(uint4*)&WaL[row * 68 + c4 * 4] = sa[t];
        }
    }
    __syncthreads();

    const int w = t >> 6, l = t & 63, lr = l & 15, lk = l >> 4;
    const int a0 = w, f2 = l;     // agg ownership: head w, feature pair 2l,2l+1

    float binv[8];
#pragma unroll
    for (int nr = 0; nr < 8; ++nr) binv[nr] = b_in[nr * 16 + lr];
    const float ba = b_a[lr & 7];

    const f32x4 z4 = {0.f, 0.f, 0.f, 0.f};
    float sum0 = 0.f, sum1 = 0.f, mx0 = -INFINITY, mx1 = -INFINITY;

    // ---- T14 prefetch: raw next-chunk x rows stay in flight through the
    // whole GEMM+agg phase; s_waitcnt lands at next iteration's pack ----
    float4 nx[8];
    {
        int row0 = min(s0 + w * 16 + lr, s1 - 1);
        const float4* p = (const float4*)(x + (size_t)row0 * 128 + lk * 8);
#pragma unroll
        for (int ks = 0; ks < 4; ++ks) {
            nx[2 * ks] = p[ks * 8];        // ks*32 floats = 8 float4
            nx[2 * ks + 1] = p[ks * 8 + 1];
        }
    }

    for (int c0 = s0; c0 < s1; c0 += 128) {
        const int rc = min(128, s1 - c0);

        bf16x8 af[4];
#pragma unroll
        for (int ks = 0; ks < 4; ++ks) af[ks] = pack8(nx[2 * ks], nx[2 * ks + 1]);

        if (c0 + 128 < s1) {   // issue next-chunk loads NOW (hide under compute)
            int nrow = min(c0 + 128 + w * 16 + lr, s1 - 1);
            const float4* p = (const float4*)(x + (size_t)nrow * 128 + lk * 8);
#pragma unroll
            for (int ks = 0; ks < 4; ++ks) {
                nx[2 * ks] = p[ks * 8];
                nx[2 * ks + 1] = p[ks * 8 + 1];
            }
        }

        // xp GEMM in two nr-halves (acc[4] not acc[8]: cap register pressure)
#pragma unroll
        for (int nh = 0; nh < 2; ++nh) {
            f32x4 acc[4];
#pragma unroll
            for (int nr = 0; nr < 4; ++nr) acc[nr] = z4;
#pragma unroll
            for (int ks = 0; ks < 4; ++ks)
#pragma unroll
                for (int nr = 0; nr < 4; ++nr) {
                    bf16x8 bfrag = *(const bf16x8*)&WbL[((nh * 4 + nr) * 16 + lr) * 68 + ks * 16 + lk * 4];
                    acc[nr] = __builtin_amdgcn_mfma_f32_16x16x32_bf16(af[ks], bfrag, acc[nr], 0, 0, 0);
                }
#pragma unroll
            for (int nr = 0; nr < 4; ++nr)
#pragma unroll
                for (int r = 0; r < 4; ++r) {
                    int row = w * 16 + lk * 4 + r;
                    XPs[row * 136 + (nh * 4 + nr) * 16 + lr] =
                        f2bfu(((const float*)&acc[nr])[r] + binv[nh * 4 + nr]);
                }
        }
        // own XP rows back as A-frags (same-wave write/read)
        bf16x8 xf[4];
#pragma unroll
        for (int ks = 0; ks < 4; ++ks)
            xf[ks] = *(const bf16x8*)&XPs[(w * 16 + lr) * 136 + ks * 32 + lk * 8];
        // score MFMA
        f32x4 sacc = z4;
#pragma unroll
        for (int ks = 0; ks < 4; ++ks) {
            bf16x8 bfrag = *(const bf16x8*)&WaL[lr * 68 + ks * 16 + lk * 4];
            sacc = __builtin_amdgcn_mfma_f32_16x16x32_bf16(xf[ks], bfrag, sacc, 0, 0, 0);
        }
        if (lr < A_HEADS) {
#pragma unroll
            for (int r = 0; r < 4; ++r) {
                int row = w * 16 + lk * 4 + r;
                scoref[row * 8 + lr] = __expf(-fabsf(((const float*)&sacc)[r] + ba));
            }
        }
        // out_part GEMM K=256 (B-frags from global bf16 Wo, L1/L2-hot)
        f32x4 aco[4];
#pragma unroll
        for (int nr = 0; nr < 4; ++nr) aco[nr] = z4;
#pragma unroll
        for (int ks = 0; ks < 4; ++ks)
#pragma unroll
            for (int nr = 0; nr < 4; ++nr) {
                bf16x8 b0 = *(const bf16x8*)&Wo[(nr * 16 + lr) * 128 + ks * 16 + lk * 4];
                aco[nr] = __builtin_amdgcn_mfma_f32_16x16x32_bf16(af[ks], b0, aco[nr], 0, 0, 0);
                bf16x8 b1 = *(const bf16x8*)&Wo[(nr * 16 + lr) * 128 + 64 + ks * 16 + lk * 4];
                aco[nr] = __builtin_amdgcn_mfma_f32_16x16x32_bf16(xf[ks], b1, aco[nr], 0, 0, 0);
            }
#pragma unroll
        for (int nr = 0; nr < 4; ++nr)
#pragma unroll
            for (int r = 0; r < 4; ++r) {
                int n = c0 + w * 16 + lk * 4 + r;
                if (n < s1)
                    opart16[(size_t)n * 64 + nr * 16 + lr] = f2bfu(((const float*)&aco[nr])[r]);
            }
        __syncthreads();   // XP + scoref visible to all waves

        // register agg: thread = (head a0, feat pair 2*f2,2*f2+1)
#pragma unroll 4
        for (int i = 0; i < rc; ++i) {
            unsigned u = XP[i * 68 + f2];
            float sa = scoref[i * 8 + a0];
            float e0 = sa * bfl(u), e1 = sa * bfh(u);
            sum0 += e0; sum1 += e1;
            mx0 = fmaxf(mx0, e0); mx1 = fmaxf(mx1, e1);
        }
        __syncthreads();   // before next chunk overwrites XP/scoref
    }

    // ---- agg vector into XPf ----
    const float inv = 1.f / (float)cnt;
    XPf[a0 * 256 + 2 * f2]           = sum0 * inv;
    XPf[a0 * 256 + 2 * f2 + 1]       = sum1 * inv;
    XPf[a0 * 256 + 128 + 2 * f2]     = mx0;
    XPf[a0 * 256 + 128 + 2 * f2 + 1] = mx1;
    __syncthreads();

    // ---- projection via bf16 Wagg: wave w -> outputs w*8..w*8+7 ----
#pragma unroll
    for (int i = 0; i < 8; ++i) {
        int o = w * 8 + i;
        const unsigned* wrow = Wagg + (size_t)o * 1024;
        float partial = 0.f;
#pragma unroll
        for (int c = 0; c < 4; ++c) {
            int j4 = c * 256 + l * 4;
            uint4 wv = *(const uint4*)&wrow[j4];
            const float* av = &XPf[2 * j4];
            partial = fmaf(bfl(wv.x), av[0], partial);
            partial = fmaf(bfh(wv.x), av[1], partial);
            partial = fmaf(bfl(wv.y), av[2], partial);
            partial = fmaf(bfh(wv.y), av[3], partial);
            partial = fmaf(bfl(wv.z), av[4], partial);
            partial = fmaf(bfh(wv.z), av[5], partial);
            partial = fmaf(bfl(wv.w), av[6], partial);
            partial = fmaf(bfh(wv.w), av[7], partial);
        }
#pragma unroll
        for (int m = 1; m < 64; m <<= 1) partial += __shfl_xor(partial, m);
        if (l == 0) projL[o] = partial + b_out[o];
    }
    __syncthreads();

    // ---- final: out = relu(out_part + projL) for own rows ----
    const int rr = t >> 3, cg = t & 7;
    float p[8];
#pragma unroll
    for (int j = 0; j < 8; ++j) p[j] = projL[cg * 8 + j];
    for (int r0 = s0; r0 < s1; r0 += 64) {
        int row = r0 + rr;
        if (row < s1) {
            uint4 v = *(const uint4*)&out_part_u32[(size_t)row * 32 + cg * 4];
            float4 o0, o1;
            o0.x = fmaxf(bfl(v.x) + p[0], 0.f);
            o0.y = fmaxf(bfh(v.x) + p[1], 0.f);
            o0.z = fmaxf(bfl(v.y) + p[2], 0.f);
            o0.w = fmaxf(bfh(v.y) + p[3], 0.f);
            o1.x = fmaxf(bfl(v.z) + p[4], 0.f);
            o1.y = fmaxf(bfh(v.z) + p[5], 0.f);
            o1.z = fmaxf(bfl(v.w) + p[6], 0.f);
            o1.w = fmaxf(bfh(v.w) + p[7], 0.f);
            *(float4*)&out[(size_t)row * 64 + cg * 8] = o0;
            *(float4*)&out[(size_t)row * 64 + cg * 8 + 4] = o1;
        }
    }
}

extern "C" void kernel_launch(void* const* d_in, const int* in_sizes, int n_in,
                              void* d_out, int out_size, void* d_ws, size_t ws_size,
                              hipStream_t stream) {
    const float* x     = (const float*)d_in[0];
    const int*   batch = (const int*)d_in[1];
    const float* W_in  = (const float*)d_in[3];
    const float* b_in  = (const float*)d_in[4];
    const float* W_a   = (const float*)d_in[5];
    const float* b_a   = (const float*)d_in[6];
    const float* W_out = (const float*)d_in[7];
    const float* b_out = (const float*)d_in[8];
    float* out = (float*)d_out;

    int* seg_start  = (int*)d_ws;                            // 520 ints
    unsigned* Wb    = (unsigned*)(seg_start + 520);          // 8192
    unsigned* Wa    = Wb + 8192;                             // 1024
    unsigned* Wo    = Wa + 1024;                             // 8192
    unsigned* Wagg  = Wo + 8192;                             // 65536
    unsigned* out_part_u32 = Wagg + 65536;                   // N*32 u32

    seg_bounds_kernel<<<1, 1024, 0, stream>>>(batch, N_NODES, seg_start);
    wconv_kernel<<<324, 256, 0, stream>>>(W_in, W_a, W_out, Wb, Wa, Wo, Wagg);
    mega_kernel<<<B_SEGS, 512, 0, stream>>>(
        x, seg_start, b_in, b_a, b_out, Wb, Wa, Wo, Wagg, out_part_u32, out);
}